// Round 1
// baseline (298.225 us; speedup 1.0000x reference)
//
#include <hip/hip_runtime.h>

#define BN   64
#define KCLS 3
#define PPIX 147456
#define NB1  4096
#define NB3  128
#define BLKS_PER_ROW 9           // 9 * 16384 = 147456
#define ELEMS_PER_BLK 16384

// ---------------- workspace layout (bytes) ----------------
static const size_t SZ_NLL  = (size_t)BN * PPIX * 4;                 // 37,748,736
static const size_t OFF_C1  = SZ_NLL;
static const size_t OFF_S1  = OFF_C1 + (size_t)BN * NB1 * 4;
static const size_t OFF_C2  = OFF_S1 + (size_t)BN * NB1 * 4;
static const size_t OFF_S2  = OFF_C2 + (size_t)BN * NB1 * 4;
static const size_t OFF_C3  = OFF_S2 + (size_t)BN * NB1 * 4;
static const size_t OFF_S3  = OFF_C3 + (size_t)BN * NB3 * 4;
static const size_t OFF_B1  = OFF_S3 + (size_t)BN * NB3 * 4;
static const size_t OFF_R1  = OFF_B1 + 256;
static const size_t OFF_B2  = OFF_R1 + 256;
static const size_t OFF_R2  = OFF_B2 + 256;
static const size_t OFF_SS  = OFF_R2 + 256;     // double[64], 8-aligned
static const size_t OFF_ACC = OFF_SS + 512;     // double accumulator
static const size_t WS_END  = OFF_ACC + 8;

__device__ __forceinline__ unsigned topk_count(const int* sp_ptr) {
    // step_percent: robust read — int 1 stays 1; float 1.0f bits (1065353216) clamps to 1.0
    double sp = (double)sp_ptr[0];
    if (sp > 1.0) sp = 1.0;
    return (unsigned)(sp * 0.15 * (double)PPIX + (1.0 - sp) * (double)PPIX);
}

// ---------------- kernel 1: gather NLL + histogram level 1 ----------------
__global__ __launch_bounds__(256) void k_nll_hist1(
    const float* __restrict__ in, const int* __restrict__ tgt,
    float* __restrict__ nll, unsigned* __restrict__ cnt1, float* __restrict__ sum1)
{
    __shared__ unsigned lc[NB1];
    __shared__ float    ls[NB1];
    const int tid = threadIdx.x;
    for (int i = tid; i < NB1; i += 256) { lc[i] = 0u; ls[i] = 0.0f; }
    __syncthreads();

    const int row   = blockIdx.x / BLKS_PER_ROW;
    const int chunk = blockIdx.x % BLKS_PER_ROW;
    const float* inr = in  + (size_t)row * KCLS * PPIX;
    const int*   tr  = tgt + (size_t)row * PPIX;
    float*       nr  = nll + (size_t)row * PPIX;
    const int base = chunk * ELEMS_PER_BLK;

    #pragma unroll 4
    for (int j = 0; j < 64; ++j) {
        const int p = base + j * 256 + tid;
        const int t = tr[p];
        float v = 0.0f;
        if (t != 255) v = -inr[(size_t)t * PPIX + p];
        v = fmaxf(v, 0.0f);                 // kill -0.0 (log-probs <= 0 always)
        nr[p] = v;
        const unsigned key = (__float_as_uint(v) >> 19) & 0xFFFu;
        atomicAdd(&lc[key], 1u);
        atomicAdd(&ls[key], v);
    }
    __syncthreads();

    unsigned* gc = cnt1 + (size_t)row * NB1;
    float*    gs = sum1 + (size_t)row * NB1;
    for (int i = tid; i < NB1; i += 256) {
        const unsigned c = lc[i];
        if (c) { atomicAdd(&gc[i], c); atomicAdd(&gs[i], ls[i]); }
    }
}

// ---------------- scan over 4096-bin histogram (descending) ----------------
// mode 0: k from step_percent, st_S[row] = S_above
// mode 1: k = st_r_in[row],    st_S[row] += S_above
__global__ __launch_bounds__(256) void k_scan(
    const unsigned* __restrict__ cnt, const float* __restrict__ sum,
    const int* __restrict__ sp_ptr, int* __restrict__ st_b, int* __restrict__ st_r,
    const int* __restrict__ st_r_in, double* __restrict__ st_S, int mode)
{
    const int row = blockIdx.x, tid = threadIdx.x;
    __shared__ unsigned csum[256];
    __shared__ double   ssum[256];
    const unsigned* c = cnt + (size_t)row * NB1;
    const float*    s = sum + (size_t)row * NB1;

    unsigned cl[16]; float slv[16];
    unsigned cacc = 0; double sacc = 0.0;
    const int base = tid * 16;
    #pragma unroll
    for (int i = 0; i < 16; ++i) {
        const int bin = NB1 - 1 - (base + i);
        cl[i]  = c[bin];
        slv[i] = s[bin];
        cacc += cl[i];
        sacc += (double)slv[i];
    }
    csum[tid] = cacc; ssum[tid] = sacc;
    __syncthreads();
    for (int off = 1; off < 256; off <<= 1) {   // Hillis–Steele inclusive scan
        unsigned cv = 0; double sv = 0.0;
        if (tid >= off) { cv = csum[tid - off]; sv = ssum[tid - off]; }
        __syncthreads();
        csum[tid] += cv; ssum[tid] += sv;
        __syncthreads();
    }

    const unsigned k = (mode == 0) ? topk_count(sp_ptr) : (unsigned)st_r_in[row];
    unsigned cum = tid ? csum[tid - 1] : 0u;
    double   sS  = tid ? ssum[tid - 1] : 0.0;
    #pragma unroll
    for (int i = 0; i < 16; ++i) {
        const unsigned cb = cl[i];
        if (cum < k && cum + cb >= k) {        // exactly one (thread,i) hits this
            const int bin = NB1 - 1 - (base + i);
            st_b[row] = bin;
            st_r[row] = (int)(k - cum);
            if (mode == 0) st_S[row] = sS; else st_S[row] += sS;
        }
        cum += cb;
        sS  += (double)slv[i];
    }
}

// ---------------- kernel 3: histogram level 2 (bits 18:7 of bin-b1 values) --
__global__ __launch_bounds__(256) void k_hist2(
    const float* __restrict__ nll, const int* __restrict__ st_b1,
    unsigned* __restrict__ cnt2, float* __restrict__ sum2)
{
    __shared__ unsigned lc[NB1];
    __shared__ float    ls[NB1];
    const int tid = threadIdx.x;
    for (int i = tid; i < NB1; i += 256) { lc[i] = 0u; ls[i] = 0.0f; }
    __syncthreads();

    const int row   = blockIdx.x / BLKS_PER_ROW;
    const int chunk = blockIdx.x % BLKS_PER_ROW;
    const unsigned b1 = (unsigned)st_b1[row];
    const float4* nr4 = (const float4*)(nll + (size_t)row * PPIX);
    const int base4 = chunk * (ELEMS_PER_BLK / 4);

    #pragma unroll 2
    for (int j = 0; j < 16; ++j) {
        const float4 f = nr4[base4 + j * 256 + tid];
        const float vv[4] = {f.x, f.y, f.z, f.w};
        #pragma unroll
        for (int q = 0; q < 4; ++q) {
            const unsigned bits = __float_as_uint(vv[q]);
            if ((bits >> 19) == b1) {
                atomicAdd(&lc[(bits >> 7) & 0xFFFu], 1u);
                atomicAdd(&ls[(bits >> 7) & 0xFFFu], vv[q]);
            }
        }
    }
    __syncthreads();
    unsigned* gc = cnt2 + (size_t)row * NB1;
    float*    gs = sum2 + (size_t)row * NB1;
    for (int i = tid; i < NB1; i += 256) {
        const unsigned c = lc[i];
        if (c) { atomicAdd(&gc[i], c); atomicAdd(&gs[i], ls[i]); }
    }
}

// ---------------- kernel 5: histogram level 3 (bits 6:0) --------------------
__global__ __launch_bounds__(256) void k_hist3(
    const float* __restrict__ nll, const int* __restrict__ st_b1, const int* __restrict__ st_b2,
    unsigned* __restrict__ cnt3, float* __restrict__ sum3)
{
    __shared__ unsigned lc[NB3];
    __shared__ float    ls[NB3];
    const int tid = threadIdx.x;
    if (tid < NB3) { lc[tid] = 0u; ls[tid] = 0.0f; }
    __syncthreads();

    const int row   = blockIdx.x / BLKS_PER_ROW;
    const int chunk = blockIdx.x % BLKS_PER_ROW;
    const unsigned pref = ((unsigned)st_b1[row] << 12) | (unsigned)st_b2[row]; // bits[30:7]
    const float4* nr4 = (const float4*)(nll + (size_t)row * PPIX);
    const int base4 = chunk * (ELEMS_PER_BLK / 4);

    #pragma unroll 2
    for (int j = 0; j < 16; ++j) {
        const float4 f = nr4[base4 + j * 256 + tid];
        const float vv[4] = {f.x, f.y, f.z, f.w};
        #pragma unroll
        for (int q = 0; q < 4; ++q) {
            const unsigned bits = __float_as_uint(vv[q]);
            if ((bits >> 7) == pref) {
                atomicAdd(&lc[bits & 0x7Fu], 1u);
                atomicAdd(&ls[bits & 0x7Fu], vv[q]);
            }
        }
    }
    __syncthreads();
    if (tid < NB3) {
        const unsigned c = lc[tid];
        if (c) {
            atomicAdd(&cnt3[(size_t)row * NB3 + tid], c);
            atomicAdd(&sum3[(size_t)row * NB3 + tid], ls[tid]);
        }
    }
}

// ---------------- kernel 6: final per-row resolve + global accumulate -------
__global__ __launch_bounds__(128) void k_final(
    const unsigned* __restrict__ cnt3, const float* __restrict__ sum3,
    const int* __restrict__ st_b1, const int* __restrict__ st_b2, const int* __restrict__ st_r2,
    const double* __restrict__ st_S, double* __restrict__ accum)
{
    const int row = blockIdx.x, tid = threadIdx.x;
    __shared__ unsigned lc[NB3];
    __shared__ float    ls[NB3];
    lc[tid] = cnt3[(size_t)row * NB3 + tid];
    ls[tid] = sum3[(size_t)row * NB3 + tid];
    __syncthreads();
    if (tid == 0) {
        const unsigned k = (unsigned)st_r2[row];
        unsigned cum = 0, r3 = 0; int b3 = 0; double S = 0.0;
        for (int bin = NB3 - 1; bin >= 0; --bin) {
            const unsigned cb = lc[bin];
            if (cum < k && cum + cb >= k) { b3 = bin; r3 = k - cum; break; }
            cum += cb;
            S   += (double)ls[bin];
        }
        const unsigned tb = ((unsigned)st_b1[row] << 19) | ((unsigned)st_b2[row] << 7) | (unsigned)b3;
        const float tval = __uint_as_float(tb);
        const double total = st_S[row] + S + (double)r3 * (double)tval;
        atomicAdd(accum, total);
    }
}

// ---------------- kernel 7: write mean --------------------------------------
__global__ void k_out(const double* __restrict__ accum, const int* __restrict__ sp_ptr,
                      float* __restrict__ out)
{
    if (threadIdx.x == 0 && blockIdx.x == 0) {
        const unsigned k = topk_count(sp_ptr);
        out[0] = (float)(accum[0] / ((double)BN * (double)k));
    }
}

extern "C" void kernel_launch(void* const* d_in, const int* in_sizes, int n_in,
                              void* d_out, int out_size, void* d_ws, size_t ws_size,
                              hipStream_t stream)
{
    const float* in  = (const float*)d_in[0];
    const int*   tgt = (const int*)d_in[1];
    const int*   sp  = (const int*)d_in[2];

    char* ws = (char*)d_ws;
    float*    nll   = (float*)ws;
    unsigned* cnt1  = (unsigned*)(ws + OFF_C1);
    float*    sum1  = (float*)(ws + OFF_S1);
    unsigned* cnt2  = (unsigned*)(ws + OFF_C2);
    float*    sum2  = (float*)(ws + OFF_S2);
    unsigned* cnt3  = (unsigned*)(ws + OFF_C3);
    float*    sum3  = (float*)(ws + OFF_S3);
    int*      st_b1 = (int*)(ws + OFF_B1);
    int*      st_r1 = (int*)(ws + OFF_R1);
    int*      st_b2 = (int*)(ws + OFF_B2);
    int*      st_r2 = (int*)(ws + OFF_R2);
    double*   st_S  = (double*)(ws + OFF_SS);
    double*   accum = (double*)(ws + OFF_ACC);

    // zero histograms + state + accumulator (ws is poisoned each call)
    hipMemsetAsync(ws + OFF_C1, 0, WS_END - OFF_C1, stream);

    const int hist_blocks = BN * BLKS_PER_ROW;   // 576
    k_nll_hist1<<<hist_blocks, 256, 0, stream>>>(in, tgt, nll, cnt1, sum1);
    k_scan<<<BN, 256, 0, stream>>>(cnt1, sum1, sp, st_b1, st_r1, nullptr, st_S, 0);
    k_hist2<<<hist_blocks, 256, 0, stream>>>(nll, st_b1, cnt2, sum2);
    k_scan<<<BN, 256, 0, stream>>>(cnt2, sum2, sp, st_b2, st_r2, st_r1, st_S, 1);
    k_hist3<<<hist_blocks, 256, 0, stream>>>(nll, st_b1, st_b2, cnt3, sum3);
    k_final<<<BN, 128, 0, stream>>>(cnt3, sum3, st_b1, st_b2, st_r2, st_S, accum);
    k_out<<<1, 64, 0, stream>>>(accum, sp, (float*)d_out);
}

// Round 2
// 279.812 us; speedup vs baseline: 1.0658x; 1.0658x over previous
//
#include <hip/hip_runtime.h>

#define BN   64
#define KCLS 3
#define PPIX 147456
#define NB1  4096
#define NB3  128
#define BLKS_PER_ROW 36          // 36 * 4096 = 147456
#define PX_PER_BLK   4096
#define F4_PER_BLK   1024        // 4096 / 4
#define CAP  32768               // candidate cap per row (expected ~2-6K)

// ---------------- workspace layout (bytes) ----------------
static const size_t OFF_CAND = 0;                                    // BN*CAP*4 = 8 MB
static const size_t OFF_C1   = OFF_CAND + (size_t)BN * CAP * 4;
static const size_t OFF_S1   = OFF_C1 + (size_t)BN * NB1 * 4;        // 1 MB
static const size_t OFF_CCNT = OFF_S1 + (size_t)BN * NB1 * 4;        // 1 MB
static const size_t OFF_B1   = OFF_CCNT + 256;
static const size_t OFF_R1   = OFF_B1 + 256;
static const size_t OFF_SS   = OFF_R1 + 256;    // double[64]
static const size_t OFF_ACC  = OFF_SS + 512;    // double accumulator
static const size_t WS_END   = OFF_ACC + 8;

__device__ __forceinline__ unsigned topk_count(const int* sp_ptr) {
    double sp = (double)sp_ptr[0];
    if (sp > 1.0) sp = 1.0;
    return (unsigned)(sp * 0.15 * (double)PPIX + (1.0 - sp) * (double)PPIX);
}

__device__ __forceinline__ float sel_nll(int t, float a, float b, float c) {
    float lp = (t == 0) ? a : (t == 1) ? b : (t == 2) ? c : 0.0f;
    return fmaxf(-lp, 0.0f);   // nll >= 0; kill -0.0
}

// ---------------- kernel 1: select NLL (3-stream) + histogram level 1 -------
__global__ __launch_bounds__(256) void k_hist1(
    const float* __restrict__ in, const int* __restrict__ tgt,
    unsigned* __restrict__ cnt1, float* __restrict__ sum1)
{
    __shared__ unsigned lc[NB1];
    __shared__ float    ls[NB1];
    const int tid = threadIdx.x;
    for (int i = tid; i < NB1; i += 256) { lc[i] = 0u; ls[i] = 0.0f; }
    __syncthreads();

    const int row   = blockIdx.x / BLKS_PER_ROW;
    const int chunk = blockIdx.x % BLKS_PER_ROW;
    const float4* p0 = (const float4*)(in + (size_t)row * KCLS * PPIX);
    const float4* p1 = p0 + PPIX / 4;
    const float4* p2 = p1 + PPIX / 4;
    const int4*   t4 = (const int4*)(tgt + (size_t)row * PPIX);
    const int base = chunk * (F4_PER_BLK);

    #pragma unroll
    for (int j = 0; j < 4; ++j) {
        const int idx = base + j * 256 + tid;
        const int4   t = t4[idx];
        const float4 a = p0[idx];
        const float4 b = p1[idx];
        const float4 c = p2[idx];
        float v[4];
        v[0] = sel_nll(t.x, a.x, b.x, c.x);
        v[1] = sel_nll(t.y, a.y, b.y, c.y);
        v[2] = sel_nll(t.z, a.z, b.z, c.z);
        v[3] = sel_nll(t.w, a.w, b.w, c.w);
        #pragma unroll
        for (int q = 0; q < 4; ++q) {
            const unsigned key = __float_as_uint(v[q]) >> 19;   // v>=0 → key<4096
            atomicAdd(&lc[key], 1u);
            atomicAdd(&ls[key], v[q]);
        }
    }
    __syncthreads();

    unsigned* gc = cnt1 + (size_t)row * NB1;
    float*    gs = sum1 + (size_t)row * NB1;
    for (int i = tid; i < NB1; i += 256) {
        const unsigned cc = lc[i];
        if (cc) { atomicAdd(&gc[i], cc); atomicAdd(&gs[i], ls[i]); }
    }
}

// ---------------- kernel 2: scan 4096-bin histogram (descending) ------------
__global__ __launch_bounds__(256) void k_scan(
    const unsigned* __restrict__ cnt, const float* __restrict__ sum,
    const int* __restrict__ sp_ptr, int* __restrict__ st_b, int* __restrict__ st_r,
    double* __restrict__ st_S)
{
    const int row = blockIdx.x, tid = threadIdx.x;
    __shared__ unsigned csum[256];
    __shared__ double   ssum[256];
    const unsigned* c = cnt + (size_t)row * NB1;
    const float*    s = sum + (size_t)row * NB1;

    unsigned cl[16]; float slv[16];
    unsigned cacc = 0; double sacc = 0.0;
    const int base = tid * 16;
    #pragma unroll
    for (int i = 0; i < 16; ++i) {
        const int bin = NB1 - 1 - (base + i);
        cl[i]  = c[bin];
        slv[i] = s[bin];
        cacc += cl[i];
        sacc += (double)slv[i];
    }
    csum[tid] = cacc; ssum[tid] = sacc;
    __syncthreads();
    for (int off = 1; off < 256; off <<= 1) {
        unsigned cv = 0; double sv = 0.0;
        if (tid >= off) { cv = csum[tid - off]; sv = ssum[tid - off]; }
        __syncthreads();
        csum[tid] += cv; ssum[tid] += sv;
        __syncthreads();
    }

    const unsigned k = topk_count(sp_ptr);
    unsigned cum = tid ? csum[tid - 1] : 0u;
    double   sS  = tid ? ssum[tid - 1] : 0.0;
    #pragma unroll
    for (int i = 0; i < 16; ++i) {
        const unsigned cb = cl[i];
        if (cum < k && cum + cb >= k) {     // exactly one (thread,i) hits
            st_b[row] = NB1 - 1 - (base + i);
            st_r[row] = (int)(k - cum);
            st_S[row] = sS;
        }
        cum += cb;
        sS  += (double)slv[i];
    }
}

// ---------------- kernel 3: compact candidates in bin b1 --------------------
__global__ __launch_bounds__(256) void k_compact(
    const float* __restrict__ in, const int* __restrict__ tgt,
    const int* __restrict__ st_b1, float* __restrict__ cand, int* __restrict__ ccnt)
{
    __shared__ float stage[PX_PER_BLK];   // worst case: all 4096 match
    __shared__ int lcnt, gbase;
    const int tid = threadIdx.x;
    if (tid == 0) lcnt = 0;
    __syncthreads();

    const int row   = blockIdx.x / BLKS_PER_ROW;
    const int chunk = blockIdx.x % BLKS_PER_ROW;
    const unsigned b1 = (unsigned)st_b1[row];
    const float4* p0 = (const float4*)(in + (size_t)row * KCLS * PPIX);
    const float4* p1 = p0 + PPIX / 4;
    const float4* p2 = p1 + PPIX / 4;
    const int4*   t4 = (const int4*)(tgt + (size_t)row * PPIX);
    const int base = chunk * (F4_PER_BLK);

    #pragma unroll
    for (int j = 0; j < 4; ++j) {
        const int idx = base + j * 256 + tid;
        const int4   t = t4[idx];
        const float4 a = p0[idx];
        const float4 b = p1[idx];
        const float4 c = p2[idx];
        float v[4];
        v[0] = sel_nll(t.x, a.x, b.x, c.x);
        v[1] = sel_nll(t.y, a.y, b.y, c.y);
        v[2] = sel_nll(t.z, a.z, b.z, c.z);
        v[3] = sel_nll(t.w, a.w, b.w, c.w);
        #pragma unroll
        for (int q = 0; q < 4; ++q) {
            if ((__float_as_uint(v[q]) >> 19) == b1) {
                const int s = atomicAdd(&lcnt, 1);
                stage[s] = v[q];
            }
        }
    }
    __syncthreads();
    if (tid == 0) gbase = atomicAdd(&ccnt[row], lcnt);
    __syncthreads();
    const int n = lcnt, gb = gbase;
    float* cr = cand + (size_t)row * CAP;
    for (int i = tid; i < n; i += 256) {
        const int pos = gb + i;
        if (pos < CAP) cr[pos] = stage[i];
    }
}

// ---------------- kernel 4: per-row resolve (levels 2+3 over candidates) ----
__global__ __launch_bounds__(256) void k_resolve(
    const float* __restrict__ cand, const int* __restrict__ ccnt,
    const int* __restrict__ st_b1, const int* __restrict__ st_r1,
    const double* __restrict__ st_S, double* __restrict__ accum)
{
    __shared__ unsigned lc[NB1];
    __shared__ float    ls[NB1];
    __shared__ unsigned csum[256];
    __shared__ double   ssum[256];
    __shared__ int sb2, sr2;
    __shared__ double sS2;

    const int row = blockIdx.x, tid = threadIdx.x;
    int n = ccnt[row]; if (n > CAP) n = CAP;
    const float* cv = cand + (size_t)row * CAP;

    // ---- level 2: hist over bits[18:7] ----
    for (int i = tid; i < NB1; i += 256) { lc[i] = 0u; ls[i] = 0.0f; }
    __syncthreads();
    for (int i = tid; i < n; i += 256) {
        const float v = cv[i];
        const unsigned key = (__float_as_uint(v) >> 7) & 0xFFFu;
        atomicAdd(&lc[key], 1u);
        atomicAdd(&ls[key], v);
    }
    __syncthreads();

    // descending scan to locate b2
    unsigned cl[16]; float slv[16];
    unsigned cacc = 0; double sacc = 0.0;
    const int base = tid * 16;
    #pragma unroll
    for (int i = 0; i < 16; ++i) {
        const int bin = NB1 - 1 - (base + i);
        cl[i]  = lc[bin];
        slv[i] = ls[bin];
        cacc += cl[i];
        sacc += (double)slv[i];
    }
    csum[tid] = cacc; ssum[tid] = sacc;
    __syncthreads();
    for (int off = 1; off < 256; off <<= 1) {
        unsigned cv2 = 0; double sv = 0.0;
        if (tid >= off) { cv2 = csum[tid - off]; sv = ssum[tid - off]; }
        __syncthreads();
        csum[tid] += cv2; ssum[tid] += sv;
        __syncthreads();
    }
    const unsigned k = (unsigned)st_r1[row];
    unsigned cum = tid ? csum[tid - 1] : 0u;
    double   sS  = tid ? ssum[tid - 1] : 0.0;
    #pragma unroll
    for (int i = 0; i < 16; ++i) {
        const unsigned cb = cl[i];
        if (cum < k && cum + cb >= k) {
            sb2 = NB1 - 1 - (base + i);
            sr2 = (int)(k - cum);
            sS2 = sS;
        }
        cum += cb;
        sS  += (double)slv[i];
    }
    __syncthreads();

    // ---- level 3: 128-bin hist over bits[6:0], prefix (b1<<12)|b2 ----
    const unsigned pref = ((unsigned)st_b1[row] << 12) | (unsigned)sb2;
    if (tid < NB3) { lc[tid] = 0u; ls[tid] = 0.0f; }
    __syncthreads();
    for (int i = tid; i < n; i += 256) {
        const float v = cv[i];
        const unsigned bits = __float_as_uint(v);
        if ((bits >> 7) == pref) {
            atomicAdd(&lc[bits & 0x7Fu], 1u);
            atomicAdd(&ls[bits & 0x7Fu], v);
        }
    }
    __syncthreads();
    if (tid == 0) {
        const unsigned k3 = (unsigned)sr2;
        unsigned cum3 = 0, r3 = 0; int b3 = 0; double S3 = 0.0;
        for (int bin = NB3 - 1; bin >= 0; --bin) {
            const unsigned cb = lc[bin];
            if (cum3 < k3 && cum3 + cb >= k3) { b3 = bin; r3 = k3 - cum3; break; }
            cum3 += cb;
            S3   += (double)ls[bin];
        }
        const float tval = __uint_as_float((pref << 7) | (unsigned)b3);
        const double total = st_S[row] + sS2 + S3 + (double)r3 * (double)tval;
        atomicAdd(accum, total);
    }
}

// ---------------- kernel 5: write mean --------------------------------------
__global__ void k_out(const double* __restrict__ accum, const int* __restrict__ sp_ptr,
                      float* __restrict__ out)
{
    if (threadIdx.x == 0 && blockIdx.x == 0) {
        const unsigned k = topk_count(sp_ptr);
        out[0] = (float)(accum[0] / ((double)BN * (double)k));
    }
}

extern "C" void kernel_launch(void* const* d_in, const int* in_sizes, int n_in,
                              void* d_out, int out_size, void* d_ws, size_t ws_size,
                              hipStream_t stream)
{
    const float* in  = (const float*)d_in[0];
    const int*   tgt = (const int*)d_in[1];
    const int*   sp  = (const int*)d_in[2];

    char* ws = (char*)d_ws;
    float*    cand  = (float*)(ws + OFF_CAND);
    unsigned* cnt1  = (unsigned*)(ws + OFF_C1);
    float*    sum1  = (float*)(ws + OFF_S1);
    int*      ccnt  = (int*)(ws + OFF_CCNT);
    int*      st_b1 = (int*)(ws + OFF_B1);
    int*      st_r1 = (int*)(ws + OFF_R1);
    double*   st_S  = (double*)(ws + OFF_SS);
    double*   accum = (double*)(ws + OFF_ACC);

    // zero histograms + counters + accumulator (~2 MB)
    hipMemsetAsync(ws + OFF_C1, 0, WS_END - OFF_C1, stream);

    const int blocks = BN * BLKS_PER_ROW;   // 2304
    k_hist1  <<<blocks, 256, 0, stream>>>(in, tgt, cnt1, sum1);
    k_scan   <<<BN, 256, 0, stream>>>(cnt1, sum1, sp, st_b1, st_r1, st_S);
    k_compact<<<blocks, 256, 0, stream>>>(in, tgt, st_b1, cand, ccnt);
    k_resolve<<<BN, 256, 0, stream>>>(cand, ccnt, st_b1, st_r1, st_S, accum);
    k_out    <<<1, 64, 0, stream>>>(accum, sp, (float*)d_out);
}

// Round 4
// 254.897 us; speedup vs baseline: 1.1700x; 1.0977x over previous
//
#include <hip/hip_runtime.h>

#define BN    64
#define KCLS  3
#define PPIX  147456
#define NB1   4096
#define NB3   128
#define BPR   36                 // blocks per row
#define PX_BLK 4096              // pixels per block
#define F4_BLK 1024              // float4 groups per block
#define CAP   8192               // candidate cap per row (expected ~2-3K)

// ---------------- workspace layout (bytes) ----------------
static const size_t OFF_NLL  = 0;                                   // 37,748,736
static const size_t OFF_CAND = OFF_NLL + (size_t)BN * PPIX * 4;     // 2 MB
static const size_t OFF_C1   = OFF_CAND + (size_t)BN * CAP * 4;     // 1 MB (zeroed)
static const size_t OFF_CCNT = OFF_C1 + (size_t)BN * NB1 * 4;       // 256 B (zeroed)
static const size_t OFF_SS   = OFF_CCNT + 256;                      // 512 B (zeroed)
static const size_t OFF_ACC  = OFF_SS + 512;                        // 8 B   (zeroed)
static const size_t ZERO_END = OFF_ACC + 8;                         // total ~40.9 MB

__device__ __forceinline__ unsigned topk_count(const int* sp_ptr) {
    double sp = (double)sp_ptr[0];
    if (sp > 1.0) sp = 1.0;
    return (unsigned)(sp * 0.15 * (double)PPIX + (1.0 - sp) * (double)PPIX);
}

__device__ __forceinline__ float sel_nll(int t, float a, float b, float c) {
    float lp = (t == 0) ? a : ((t == 1) ? b : ((t == 2) ? c : 0.0f));
    return fmaxf(-lp, 0.0f);   // nll >= 0; kill -0.0
}

// ---------------- kernel 1: NLL select + store + count histogram ------------
__global__ __launch_bounds__(256) void k_hist1(
    const float* __restrict__ in, const int* __restrict__ tgt,
    float* __restrict__ nll, unsigned* __restrict__ cnt1)
{
    __shared__ unsigned lc[NB1];   // 16 KB only -> 8+ blocks/CU
    const int tid = threadIdx.x;
    for (int i = tid; i < NB1; i += 256) lc[i] = 0u;
    __syncthreads();

    const int row   = blockIdx.x / BPR;
    const int chunk = blockIdx.x % BPR;
    const float4* p0 = (const float4*)(in + (size_t)row * KCLS * PPIX);
    const float4* p1 = p0 + PPIX / 4;
    const float4* p2 = p1 + PPIX / 4;
    const int4*   t4 = (const int4*)(tgt + (size_t)row * PPIX);
    float4*       n4 = (float4*)(nll + (size_t)row * PPIX);
    const int base = chunk * F4_BLK;

    #pragma unroll
    for (int j = 0; j < 4; ++j) {
        const int idx = base + j * 256 + tid;
        const int4   t = t4[idx];
        const float4 a = p0[idx];
        const float4 b = p1[idx];
        const float4 c = p2[idx];
        float4 v;
        v.x = sel_nll(t.x, a.x, b.x, c.x);
        v.y = sel_nll(t.y, a.y, b.y, c.y);
        v.z = sel_nll(t.z, a.z, b.z, c.z);
        v.w = sel_nll(t.w, a.w, b.w, c.w);
        n4[idx] = v;
        atomicAdd(&lc[__float_as_uint(v.x) >> 19], 1u);
        atomicAdd(&lc[__float_as_uint(v.y) >> 19], 1u);
        atomicAdd(&lc[__float_as_uint(v.z) >> 19], 1u);
        atomicAdd(&lc[__float_as_uint(v.w) >> 19], 1u);
    }
    __syncthreads();

    unsigned* gc = cnt1 + (size_t)row * NB1;
    for (int i = tid; i < NB1; i += 256) {
        const unsigned cc = lc[i];
        if (cc) atomicAdd(&gc[i], cc);
    }
}

// ---------------- kernel 2: per-row descending scan -> (b1, r1) -------------
__global__ __launch_bounds__(256) void k_scan(
    const unsigned* __restrict__ cnt, const int* __restrict__ sp_ptr,
    int* __restrict__ st_b, int* __restrict__ st_r)
{
    const int row = blockIdx.x, tid = threadIdx.x;
    __shared__ unsigned csum[256];
    const unsigned* c = cnt + (size_t)row * NB1;

    unsigned cl[16]; unsigned cacc = 0;
    const int base = tid * 16;
    #pragma unroll
    for (int i = 0; i < 16; ++i) {
        cl[i] = c[NB1 - 1 - (base + i)];
        cacc += cl[i];
    }
    csum[tid] = cacc;
    __syncthreads();
    for (int off = 1; off < 256; off <<= 1) {
        unsigned t2 = (tid >= off) ? csum[tid - off] : 0u;
        __syncthreads();
        csum[tid] += t2;
        __syncthreads();
    }
    const unsigned k = topk_count(sp_ptr);
    unsigned cum = tid ? csum[tid - 1] : 0u;
    #pragma unroll
    for (int i = 0; i < 16; ++i) {
        const unsigned cb = cl[i];
        if (cum < k && cum + cb >= k) {      // exactly one (thread,i) hits
            st_b[row] = NB1 - 1 - (base + i);
            st_r[row] = (int)(k - cum);
        }
        cum += cb;
    }
}

// ---------------- kernel 3: S_above (f64) + compact bin-b1 candidates -------
__global__ __launch_bounds__(256) void k_compact(
    const float* __restrict__ nll, const int* __restrict__ st_b1,
    float* __restrict__ cand, int* __restrict__ ccnt, double* __restrict__ st_S)
{
    __shared__ float  stage[PX_BLK];   // worst case: all 4096 match (16 KB)
    __shared__ double dred[256];       // 2 KB
    __shared__ int lcnt, gbase;
    const int tid = threadIdx.x;
    if (tid == 0) lcnt = 0;
    __syncthreads();

    const int row   = blockIdx.x / BPR;
    const int chunk = blockIdx.x % BPR;
    const unsigned b1 = (unsigned)st_b1[row];
    const unsigned lo = b1 << 19;
    const unsigned hi = (b1 + 1u) << 19;   // unsigned compare: b1==4095 -> 0x80000000 > all v>=0
    const float4* n4 = (const float4*)(nll + (size_t)row * PPIX);
    const int base = chunk * F4_BLK;

    double acc = 0.0;
    #pragma unroll
    for (int j = 0; j < 4; ++j) {
        const float4 f = n4[base + j * 256 + tid];
        const float vv[4] = {f.x, f.y, f.z, f.w};
        #pragma unroll
        for (int q = 0; q < 4; ++q) {
            const unsigned u = __float_as_uint(vv[q]);
            if (u >= hi) {
                acc += (double)vv[q];
            } else if (u >= lo) {
                const int s = atomicAdd(&lcnt, 1);
                stage[s] = vv[q];
            }
        }
    }
    dred[tid] = acc;
    __syncthreads();
    for (int s = 128; s > 0; s >>= 1) {
        if (tid < s) dred[tid] += dred[tid + s];
        __syncthreads();
    }
    if (tid == 0) {
        atomicAdd(&st_S[row], dred[0]);            // native f64 global atomic
        gbase = atomicAdd(&ccnt[row], lcnt);
    }
    __syncthreads();
    const int n = lcnt, gb = gbase;
    float* cr = cand + (size_t)row * CAP;
    for (int i = tid; i < n; i += 256) {
        const int pos = gb + i;
        if (pos < CAP) cr[pos] = stage[i];
    }
}

// ---------------- kernel 4: per-row resolve (levels 2+3 over candidates) ----
__global__ __launch_bounds__(256) void k_resolve(
    const float* __restrict__ cand, const int* __restrict__ ccnt,
    const int* __restrict__ st_b1, const int* __restrict__ st_r1,
    const double* __restrict__ st_S, double* __restrict__ accum)
{
    __shared__ unsigned lc[NB1];
    __shared__ float    ls[NB1];
    __shared__ unsigned csum[256];
    __shared__ double   ssum[256];
    __shared__ int sb2, sr2;
    __shared__ double sS2;

    const int row = blockIdx.x, tid = threadIdx.x;
    int n = ccnt[row]; if (n > CAP) n = CAP;
    const float* cv = cand + (size_t)row * CAP;

    // ---- level 2: hist over bits[18:7] ----
    for (int i = tid; i < NB1; i += 256) { lc[i] = 0u; ls[i] = 0.0f; }
    __syncthreads();
    for (int i = tid; i < n; i += 256) {
        const float v = cv[i];
        const unsigned key = (__float_as_uint(v) >> 7) & 0xFFFu;
        atomicAdd(&lc[key], 1u);
        atomicAdd(&ls[key], v);
    }
    __syncthreads();

    unsigned cl[16]; float slv[16];
    unsigned cacc = 0; double sacc = 0.0;
    const int base = tid * 16;
    #pragma unroll
    for (int i = 0; i < 16; ++i) {
        const int bin = NB1 - 1 - (base + i);
        cl[i]  = lc[bin];
        slv[i] = ls[bin];
        cacc += cl[i];
        sacc += (double)slv[i];
    }
    csum[tid] = cacc; ssum[tid] = sacc;
    __syncthreads();
    for (int off = 1; off < 256; off <<= 1) {
        unsigned cv2 = 0; double sv = 0.0;
        if (tid >= off) { cv2 = csum[tid - off]; sv = ssum[tid - off]; }
        __syncthreads();
        csum[tid] += cv2; ssum[tid] += sv;
        __syncthreads();
    }
    const unsigned k = (unsigned)st_r1[row];
    unsigned cum = tid ? csum[tid - 1] : 0u;
    double   sS  = tid ? ssum[tid - 1] : 0.0;
    #pragma unroll
    for (int i = 0; i < 16; ++i) {
        const unsigned cb = cl[i];
        if (cum < k && cum + cb >= k) {
            sb2 = NB1 - 1 - (base + i);
            sr2 = (int)(k - cum);
            sS2 = sS;
        }
        cum += cb;
        sS  += (double)slv[i];
    }
    __syncthreads();

    // ---- level 3: 128-bin hist over bits[6:0], prefix = bits[30:7] ----
    const unsigned pref = ((unsigned)st_b1[row] << 12) | (unsigned)sb2;
    if (tid < NB3) { lc[tid] = 0u; ls[tid] = 0.0f; }
    __syncthreads();
    for (int i = tid; i < n; i += 256) {
        const float v = cv[i];
        const unsigned bits = __float_as_uint(v);
        if ((bits >> 7) == pref) {
            atomicAdd(&lc[bits & 0x7Fu], 1u);
            atomicAdd(&ls[bits & 0x7Fu], v);
        }
    }
    __syncthreads();
    if (tid == 0) {
        const unsigned k3 = (unsigned)sr2;
        unsigned cum3 = 0, r3 = 0; int b3 = 0; double S3 = 0.0;
        for (int bin = NB3 - 1; bin >= 0; --bin) {
            const unsigned cb = lc[bin];
            if (cum3 < k3 && cum3 + cb >= k3) { b3 = bin; r3 = k3 - cum3; break; }
            cum3 += cb;
            S3   += (double)ls[bin];
        }
        const float tval = __uint_as_float((pref << 7) | (unsigned)b3);
        const double total = st_S[row] + sS2 + S3 + (double)r3 * (double)tval;
        atomicAdd(accum, total);
    }
}

// ---------------- kernel 5: write mean --------------------------------------
__global__ void k_out(const double* __restrict__ accum, const int* __restrict__ sp_ptr,
                      float* __restrict__ out)
{
    if (threadIdx.x == 0 && blockIdx.x == 0) {
        const unsigned k = topk_count(sp_ptr);
        out[0] = (float)(accum[0] / ((double)BN * (double)k));
    }
}

extern "C" void kernel_launch(void* const* d_in, const int* in_sizes, int n_in,
                              void* d_out, int out_size, void* d_ws, size_t ws_size,
                              hipStream_t stream)
{
    const float* in  = (const float*)d_in[0];
    const int*   tgt = (const int*)d_in[1];
    const int*   sp  = (const int*)d_in[2];

    char* ws = (char*)d_ws;
    float*    nll   = (float*)(ws + OFF_NLL);
    float*    cand  = (float*)(ws + OFF_CAND);
    unsigned* cnt1  = (unsigned*)(ws + OFF_C1);
    int*      ccnt  = (int*)(ws + OFF_CCNT);
    double*   st_S  = (double*)(ws + OFF_SS);
    double*   accum = (double*)(ws + OFF_ACC);
    int*      st_b1 = (int*)(ws + OFF_CCNT + 64 * 4);   // reuse ccnt tail (256B holds 64 ints)
    // st_b1/st_r1 need their own storage; place after ZERO_END
    st_b1 = (int*)(ws + ZERO_END);
    int*  st_r1 = (int*)(ws + ZERO_END + 256);

    // zero: cnt1 + ccnt + st_S + accum
    hipMemsetAsync(ws + OFF_C1, 0, ZERO_END - OFF_C1, stream);

    const int blocks = BN * BPR;   // 2304
    k_hist1  <<<blocks, 256, 0, stream>>>(in, tgt, nll, cnt1);
    k_scan   <<<BN, 256, 0, stream>>>(cnt1, sp, st_b1, st_r1);
    k_compact<<<blocks, 256, 0, stream>>>(nll, st_b1, cand, ccnt, st_S);
    k_resolve<<<BN, 256, 0, stream>>>(cand, ccnt, st_b1, st_r1, st_S, accum);
    k_out    <<<1, 64, 0, stream>>>(accum, sp, (float*)d_out);
}